// Round 1
// baseline (506.755 us; speedup 1.0000x reference)
//
#include <hip/hip_runtime.h>

// Problem constants (from reference)
constexpr int B_     = 4;
constexpr int N_UP   = 16384;
constexpr int N_DOWN = 4096;
constexpr int C_UP_  = 384;
constexpr int C_DOWN_= 512;
constexpr int C_OUT_ = 512;

// KNN chunking
constexpr int S_CHUNKS = 16;               // candidate chunks
constexpr int CH       = N_DOWN / S_CHUNKS; // 256 candidates per chunk

typedef __attribute__((ext_vector_type(8))) short bf16x8;
typedef __attribute__((ext_vector_type(4))) float f32x4;

// f32 -> bf16 round-to-nearest-even (bit-exact, no API dependence)
__device__ inline unsigned short f2bf(float f) {
    unsigned int u = __float_as_uint(f);
    return (unsigned short)((u + 0x7FFFu + ((u >> 16) & 1u)) >> 16);
}

// async global->LDS, 16B per lane. HW: dest = wave-uniform base + lane*16,
// so lds must be computed as base + lane*16 in lane order (it is, below).
__device__ inline void load_lds_128(const void* g, void* l) {
    __builtin_amdgcn_global_load_lds(
        (const __attribute__((address_space(1))) unsigned int*)g,
        (__attribute__((address_space(3))) unsigned int*)l, 16, 0, 0);
}

// ---------------------------------------------------------------------------
// pts4[b][m] = {x, y, z, (x*x+y*y)+z*z}   (ref rounding order, no contract)
// ---------------------------------------------------------------------------
__global__ void prep_pts4(const float* __restrict__ down_pts, float4* __restrict__ pts4) {
#pragma clang fp contract(off)
    const int i = blockIdx.x * 256 + threadIdx.x;   // 0 .. B*N_DOWN-1
    const float x = down_pts[i * 3 + 0];
    const float y = down_pts[i * 3 + 1];
    const float z = down_pts[i * 3 + 2];
    float4 p; p.x = x; p.y = y; p.z = z; p.w = (x * x + y * y) + z * z;
    pts4[i] = p;
}

// ---------------------------------------------------------------------------
// Per-chunk exact top-3. Grid (N_UP/1024, B, S_CHUNKS); 4 queries per thread.
// dist = (u2 + d2) - 2*cross, cross = (px*sx+py*sy)+pz*sz -- bit-identical
// to the np/XLA ref: fmaf(-2, cr, s) rounds once on s - 2*cr where 2*cr is
// exact (power-of-two scale), so it equals s - (2.0f*cr) bitwise.
// Top-3 insert is fully predicated (v_cmp + v_cndmask), strict < so ties
// keep the earlier (lower) index, matching top_k tie-breaking.
// ---------------------------------------------------------------------------
constexpr int QPT = 4;   // queries per thread

__launch_bounds__(256)
__global__ void knn_chunk(const float* __restrict__ up_pts,   // [B,N_UP,3]
                          const float4* __restrict__ pts4,    // [B,N_DOWN]
                          float* __restrict__ part_d,         // [B*N_UP, S*3]
                          int*   __restrict__ part_i)
{
#pragma clang fp contract(off)
    __shared__ float4 sp[CH];

    const int b = blockIdx.y;
    const int s = blockIdx.z;
    const int mbase = s * CH;
    const float4* src = pts4 + (size_t)b * N_DOWN + mbase;
    if (threadIdx.x < CH) sp[threadIdx.x] = src[threadIdx.x];
    __syncthreads();

    const int n0 = blockIdx.x * (256 * QPT);

    float qx[QPT], qy[QPT], qz[QPT], qu[QPT];
    float d0[QPT], d1[QPT], d2[QPT];
    int   i0[QPT], i1[QPT], i2[QPT];

#pragma unroll
    for (int q = 0; q < QPT; ++q) {
        const int g = b * N_UP + n0 + threadIdx.x + q * 256;
        const float x = up_pts[(size_t)g * 3 + 0];
        const float y = up_pts[(size_t)g * 3 + 1];
        const float z = up_pts[(size_t)g * 3 + 2];
        qx[q] = x; qy[q] = y; qz[q] = z;
        qu[q] = (x * x + y * y) + z * z;
        d0[q] = 1e30f; d1[q] = 1e30f; d2[q] = 1e30f;
        i0[q] = 0;     i1[q] = 0;     i2[q] = 0;
    }

    for (int m = 0; m < CH; ++m) {
        const float4 p = sp[m];
        const int gi = mbase + m;
#pragma unroll
        for (int q = 0; q < QPT; ++q) {
            const float cr = (qx[q] * p.x + qy[q] * p.y) + qz[q] * p.z;
            const float d  = __builtin_fmaf(-2.0f, cr, qu[q] + p.w);
            const bool c2 = d < d2[q];
            const bool c1 = d < d1[q];
            const bool c0 = d < d0[q];
            // straight-line sorted insert; reads of old d1/d0 happen before
            // their updates (sequential assignments below).
            d2[q] = c1 ? d1[q] : (c2 ? d  : d2[q]);
            i2[q] = c1 ? i1[q] : (c2 ? gi : i2[q]);
            d1[q] = c0 ? d0[q] : (c1 ? d  : d1[q]);
            i1[q] = c0 ? i0[q] : (c1 ? gi : i1[q]);
            d0[q] = c0 ? d  : d0[q];
            i0[q] = c0 ? gi : i0[q];
        }
    }

#pragma unroll
    for (int q = 0; q < QPT; ++q) {
        const int g = b * N_UP + n0 + threadIdx.x + q * 256;
        float* pd = part_d + (size_t)g * (S_CHUNKS * 3) + s * 3;
        int*   pi = part_i + (size_t)g * (S_CHUNKS * 3) + s * 3;
        pd[0] = d0[q]; pd[1] = d1[q]; pd[2] = d2[q];
        pi[0] = i0[q]; pi[1] = i1[q]; pi[2] = i2[q];
    }
}

// ---------------------------------------------------------------------------
// Merge S*3 exact candidates (ascending chunk = ascending index => identical
// tie-breaks to the full scan), compute normalized inverse-distance weights.
// ---------------------------------------------------------------------------
__launch_bounds__(256)
__global__ void knn_merge(const float* __restrict__ part_d,
                          const int*   __restrict__ part_i,
                          int*  __restrict__ idx_out,   // [B*N_UP,3]
                          float* __restrict__ w_out)    // [B*N_UP,3]
{
    const int g = blockIdx.x * 256 + threadIdx.x;
    const float4* pd = (const float4*)(part_d + (size_t)g * (S_CHUNKS * 3));
    const int4*   pi = (const int4*)(part_i + (size_t)g * (S_CHUNKS * 3));

    float d0 = 1e30f, d1 = 1e30f, d2 = 1e30f;
    int   i0 = 0,     i1 = 0,     i2 = 0;

#pragma unroll
    for (int q = 0; q < (S_CHUNKS * 3) / 4; ++q) {
        const float4 dv = pd[q];
        const int4   iv = pi[q];
        const float dd[4] = {dv.x, dv.y, dv.z, dv.w};
        const int   ii[4] = {iv.x, iv.y, iv.z, iv.w};
#pragma unroll
        for (int j = 0; j < 4; ++j) {
            const float d = dd[j];
            const int   m = ii[j];
            const bool c2 = d < d2;
            const bool c1 = d < d1;
            const bool c0 = d < d0;
            d2 = c1 ? d1 : (c2 ? d : d2);
            i2 = c1 ? i1 : (c2 ? m : i2);
            d1 = c0 ? d0 : (c1 ? d : d1);
            i1 = c0 ? i0 : (c1 ? m : i1);
            d0 = c0 ? d : d0;
            i0 = c0 ? m : i0;
        }
    }

    const float w0 = 1.0f / (d0 + 1e-8f);
    const float w1 = 1.0f / (d1 + 1e-8f);
    const float w2 = 1.0f / (d2 + 1e-8f);
    const float s  = (w0 + w1) + w2;
    idx_out[(size_t)g * 3 + 0] = i0;
    idx_out[(size_t)g * 3 + 1] = i1;
    idx_out[(size_t)g * 3 + 2] = i2;
    w_out[(size_t)g * 3 + 0] = w0 / s;
    w_out[(size_t)g * 3 + 1] = w1 / s;
    w_out[(size_t)g * 3 + 2] = w2 / s;
}

// ---------------------------------------------------------------------------
// f32 -> bf16 conversion, 4 elements/thread
// ---------------------------------------------------------------------------
__launch_bounds__(256)
__global__ void cvt_bf16(const float* __restrict__ src, unsigned short* __restrict__ dst) {
    const size_t i = (size_t)blockIdx.x * 256 + threadIdx.x;
    const float4 v = ((const float4*)src)[i];
    ushort4 o;
    o.x = f2bf(v.x); o.y = f2bf(v.y); o.z = f2bf(v.z); o.w = f2bf(v.w);
    ((ushort4*)dst)[i] = o;
}

// ---------------------------------------------------------------------------
// bf16 MFMA GEMM: C[m,n] = sum_k A[m,k]*W[n,k] (+bias) (+interp gather)
// 128x128 tile, BK=32, 256 threads = 4 waves (2x2 of 64x64), 16x16x32 MFMA.
// m97-style global_load_lds width-16 staging.
// ---------------------------------------------------------------------------
template<bool INTERP>
__launch_bounds__(256)
__global__ void gemm_bf16(const unsigned short* __restrict__ A,  // [M,K] bf16
                          const unsigned short* __restrict__ W,  // [N,K] bf16
                          const float* __restrict__ bias,        // [N]
                          float* __restrict__ C,                 // [M,N] f32
                          const int K, const int N,
                          const int* __restrict__ knn_idx,       // [M,3]
                          const float* __restrict__ knn_w,       // [M,3]
                          const float* __restrict__ down_f)      // [B*N_DOWN,N]
{
    __shared__ __align__(16) unsigned short As[128 * 32];
    __shared__ __align__(16) unsigned short Bs[128 * 32];
    __shared__ int   sI[128 * 3];
    __shared__ float sV[128 * 3];

    const int tid  = threadIdx.x;
    const int lane = tid & 63;
    const int wv   = tid >> 6;
    const int wrow = (wv >> 1) * 64;
    const int wcol = (wv & 1) * 64;
    const int quad = lane >> 4;
    const int l16  = lane & 15;
    const int m0   = blockIdx.y * 128;
    const int n0   = blockIdx.x * 128;

    if (INTERP) {
        for (int t = tid; t < 384; t += 256) {
            sI[t] = knn_idx[(size_t)m0 * 3 + t];
            sV[t] = knn_w[(size_t)m0 * 3 + t];
        }
    }

    f32x4 acc[4][4];
#pragma unroll
    for (int i = 0; i < 4; ++i)
#pragma unroll
        for (int j = 0; j < 4; ++j) {
            acc[i][j][0] = 0.f; acc[i][j][1] = 0.f;
            acc[i][j][2] = 0.f; acc[i][j][3] = 0.f;
        }

    // staging geometry: LDS tile is [row][32k] bf16 (64 B rows); each wave
    // covers 2 KiB as two 1 KiB chunks of lane*16.
    const int o0 = wv * 2048 + lane * 16;
    const int o1 = o0 + 1024;
    const int r0 = o0 >> 6, kk0 = o0 & 63;
    const int r1 = o1 >> 6, kk1 = o1 & 63;
    const char* Ab = (const char*)A;
    const char* Wb = (const char*)W;
    const size_t Ks = (size_t)K;

    for (int k0 = 0; k0 < K; k0 += 32) {
        __syncthreads();   // previous iter's ds_reads done before overwrite
        load_lds_128(Ab + ((size_t)(m0 + r0) * Ks + k0) * 2 + kk0, (char*)As + o0);
        load_lds_128(Ab + ((size_t)(m0 + r1) * Ks + k0) * 2 + kk1, (char*)As + o1);
        load_lds_128(Wb + ((size_t)(n0 + r0) * Ks + k0) * 2 + kk0, (char*)Bs + o0);
        load_lds_128(Wb + ((size_t)(n0 + r1) * Ks + k0) * 2 + kk1, (char*)Bs + o1);
        __syncthreads();   // vmcnt(0) drained by compiler before barrier

        bf16x8 af[4], bw[4];
#pragma unroll
        for (int i = 0; i < 4; ++i)
            af[i] = *(const bf16x8*)(As + (wrow + i * 16 + l16) * 32 + quad * 8);
#pragma unroll
        for (int j = 0; j < 4; ++j)
            bw[j] = *(const bf16x8*)(Bs + (wcol + j * 16 + l16) * 32 + quad * 8);
#pragma unroll
        for (int i = 0; i < 4; ++i)
#pragma unroll
            for (int j = 0; j < 4; ++j)
                acc[i][j] = __builtin_amdgcn_mfma_f32_16x16x32_bf16(
                    af[i], bw[j], acc[i][j], 0, 0, 0);
    }

    float bv[4];
#pragma unroll
    for (int j = 0; j < 4; ++j) bv[j] = bias[n0 + wcol + j * 16 + l16];

#pragma unroll
    for (int i = 0; i < 4; ++i) {
#pragma unroll
        for (int r = 0; r < 4; ++r) {
            const int row = m0 + wrow + i * 16 + quad * 4 + r;  // C/D: row=quad*4+reg
            float* crow = C + (size_t)row * N;
            if (INTERP) {
                const int lr3  = (row - m0) * 3;
                const int base = (row >> 14) * N_DOWN;          // batch * N_DOWN
                const float w0 = sV[lr3 + 0], w1 = sV[lr3 + 1], w2 = sV[lr3 + 2];
                const float* f0 = down_f + (size_t)(base + sI[lr3 + 0]) * N;
                const float* f1 = down_f + (size_t)(base + sI[lr3 + 1]) * N;
                const float* f2 = down_f + (size_t)(base + sI[lr3 + 2]) * N;
#pragma unroll
                for (int j = 0; j < 4; ++j) {
                    const int c = n0 + wcol + j * 16 + l16;     // C/D: col=lane&15
                    crow[c] = acc[i][j][r] + bv[j] + w0 * f0[c] + w1 * f1[c] + w2 * f2[c];
                }
            } else {
#pragma unroll
                for (int j = 0; j < 4; ++j) {
                    const int c = n0 + wcol + j * 16 + l16;
                    crow[c] = acc[i][j][r] + bv[j];
                }
            }
        }
    }
}

// ---------------------------------------------------------------------------
extern "C" void kernel_launch(void* const* d_in, const int* in_sizes, int n_in,
                              void* d_out, int out_size, void* d_ws, size_t ws_size,
                              hipStream_t stream) {
    const float* up_points     = (const float*)d_in[0];
    const float* up_features   = (const float*)d_in[1];
    const float* down_points   = (const float*)d_in[2];
    const float* down_features = (const float*)d_in[3];
    const float* W_up          = (const float*)d_in[4];
    const float* b_up          = (const float*)d_in[5];
    const float* W_down        = (const float*)d_in[6];
    const float* b_down        = (const float*)d_in[7];
    float* out = (float*)d_out;

    // workspace layout (all offsets 256B-aligned by construction)
    char* ws = (char*)d_ws;
    size_t off = 0;
    float* down_f = (float*)(ws + off);             off += (size_t)B_ * N_DOWN * C_OUT_ * 4;      // 33.6 MB
    int*   knn_idx = (int*)(ws + off);              off += (size_t)B_ * N_UP * 3 * 4;             // 0.8 MB
    float* knn_w   = (float*)(ws + off);            off += (size_t)B_ * N_UP * 3 * 4;             // 0.8 MB
    float* part_d  = (float*)(ws + off);            off += (size_t)B_ * N_UP * S_CHUNKS * 3 * 4;  // 12.6 MB
    int*   part_i  = (int*)(ws + off);              off += (size_t)B_ * N_UP * S_CHUNKS * 3 * 4;  // 12.6 MB
    float4* pts4   = (float4*)(ws + off);           off += (size_t)B_ * N_DOWN * 16;              // 0.26 MB
    unsigned short* upf_bf = (unsigned short*)(ws + off); off += (size_t)B_ * N_UP * C_UP_ * 2;   // 50.3 MB
    unsigned short* dnf_bf = (unsigned short*)(ws + off); off += (size_t)B_ * N_DOWN * C_DOWN_ * 2; // 16.8 MB
    unsigned short* wup_bf = (unsigned short*)(ws + off); off += (size_t)C_OUT_ * C_UP_ * 2;      // 0.4 MB
    unsigned short* wdn_bf = (unsigned short*)(ws + off); off += (size_t)C_OUT_ * C_DOWN_ * 2;    // 0.5 MB

    // 1) KNN pipeline
    prep_pts4<<<(B_ * N_DOWN) / 256, 256, 0, stream>>>(down_points, pts4);
    knn_chunk<<<dim3(N_UP / (256 * QPT), B_, S_CHUNKS), 256, 0, stream>>>(
        up_points, pts4, part_d, part_i);
    knn_merge<<<(B_ * N_UP) / 256, 256, 0, stream>>>(part_d, part_i, knn_idx, knn_w);

    // 2) f32 -> bf16 conversions
    cvt_bf16<<<(B_ * N_UP * C_UP_) / 1024, 256, 0, stream>>>(up_features, upf_bf);
    cvt_bf16<<<(B_ * N_DOWN * C_DOWN_) / 1024, 256, 0, stream>>>(down_features, dnf_bf);
    cvt_bf16<<<(C_OUT_ * C_UP_) / 1024, 256, 0, stream>>>(W_up, wup_bf);
    cvt_bf16<<<(C_OUT_ * C_DOWN_) / 1024, 256, 0, stream>>>(W_down, wdn_bf);

    // 3) down_f = down_features @ W_down^T + b_down   [B*N_DOWN, 512]
    gemm_bf16<false><<<dim3(C_OUT_ / 128, (B_ * N_DOWN) / 128), 256, 0, stream>>>(
        dnf_bf, wdn_bf, b_down, down_f, C_DOWN_, C_OUT_, nullptr, nullptr, nullptr);

    // 4) out = up_features @ W_up^T + b_up + interp(down_f)   [B*N_UP, 512]
    gemm_bf16<true><<<dim3(C_OUT_ / 128, (B_ * N_UP) / 128), 256, 0, stream>>>(
        upf_bf, wup_bf, b_up, out, C_UP_, C_OUT_, knn_idx, knn_w, down_f);
}

// Round 2
// 457.917 us; speedup vs baseline: 1.1067x; 1.1067x over previous
//
#include <hip/hip_runtime.h>

// Problem constants (from reference)
constexpr int B_     = 4;
constexpr int N_UP   = 16384;
constexpr int N_DOWN = 4096;
constexpr int C_UP_  = 384;
constexpr int C_DOWN_= 512;
constexpr int C_OUT_ = 512;

// KNN chunking
constexpr int S_CHUNKS = 8;                // candidate chunks
constexpr int CH       = N_DOWN / S_CHUNKS; // 512 candidates per chunk

typedef __attribute__((ext_vector_type(8))) short bf16x8;
typedef __attribute__((ext_vector_type(4))) float f32x4;

// f32 -> bf16 round-to-nearest-even (bit-exact, no API dependence)
__device__ inline unsigned short f2bf(float f) {
    unsigned int u = __float_as_uint(f);
    return (unsigned short)((u + 0x7FFFu + ((u >> 16) & 1u)) >> 16);
}

// async global->LDS, 16B per lane. HW: dest = wave-uniform base + lane*16,
// so lds must be computed as base + lane*16 in lane order (it is, below).
__device__ inline void load_lds_128(const void* g, void* l) {
    __builtin_amdgcn_global_load_lds(
        (const __attribute__((address_space(1))) unsigned int*)g,
        (__attribute__((address_space(3))) unsigned int*)l, 16, 0, 0);
}

// ---------------------------------------------------------------------------
// pts4[b][m] = {x, y, z, (x*x+y*y)+z*z}   (ref rounding order, no contract)
// ---------------------------------------------------------------------------
__global__ void prep_pts4(const float* __restrict__ down_pts, float4* __restrict__ pts4) {
#pragma clang fp contract(off)
    const int i = blockIdx.x * 256 + threadIdx.x;   // 0 .. B*N_DOWN-1
    const float x = down_pts[i * 3 + 0];
    const float y = down_pts[i * 3 + 1];
    const float z = down_pts[i * 3 + 2];
    float4 p; p.x = x; p.y = y; p.z = z; p.w = (x * x + y * y) + z * z;
    pts4[i] = p;
}

// ---------------------------------------------------------------------------
// Per-chunk exact top-3. Grid (N_UP/256, B, S_CHUNKS); 1 query per thread.
// dist = fmaf(-2, cross, u2 + d2), cross = (px*sx+py*sy)+pz*sz -- bit-
// identical to the ref's (u2+d2) - 2*cross (2*cross exact, single rounding).
//
// Distance tuple update is branchless min/med3 (3 ops, stable-insert-exact,
// incl. exact ties: d==d0 -> slot1, d==d1 -> slot2, matching strict-< insert).
// Index tuple update only fires when d < d2 (~55% of wave-iterations taken),
// and under that exec mask needs only 4 cndmasks.
// ---------------------------------------------------------------------------
__launch_bounds__(256)
__global__ void knn_chunk(const float* __restrict__ up_pts,   // [B,N_UP,3]
                          const float4* __restrict__ pts4,    // [B,N_DOWN]
                          float* __restrict__ part_d,         // [B*N_UP, S*3]
                          int*   __restrict__ part_i)
{
#pragma clang fp contract(off)
    __shared__ float4 sp[CH];

    const int b = blockIdx.y;
    const int s = blockIdx.z;
    const int mbase = s * CH;
    const float4* src = pts4 + (size_t)b * N_DOWN + mbase;
    sp[threadIdx.x]       = src[threadIdx.x];
    sp[threadIdx.x + 256] = src[threadIdx.x + 256];
    __syncthreads();

    const int n0 = blockIdx.x * 256;
    const int g  = b * N_UP + n0 + threadIdx.x;

    const float qx = up_pts[(size_t)g * 3 + 0];
    const float qy = up_pts[(size_t)g * 3 + 1];
    const float qz = up_pts[(size_t)g * 3 + 2];
    const float qu = (qx * qx + qy * qy) + qz * qz;

    float d0 = 1e30f, d1 = 1e30f, d2 = 1e30f;
    int   i0 = 0,     i1 = 0,     i2 = 0;

#pragma unroll 4
    for (int m = 0; m < CH; ++m) {
        const float4 p = sp[m];
        const int gi = mbase + m;
        const float cr = (qx * p.x + qy * p.y) + qz * p.z;
        const float d  = __builtin_fmaf(-2.0f, cr, qu + p.w);

        const bool c2 = d < d2;
        const bool c1 = d < d1;
        const bool c0 = d < d0;

        // index update: rare-ish, exec-masked by c2; 4 cndmasks inside.
        if (c2) {
            i2 = c1 ? i1 : gi;                 // uses old i1
            i1 = c0 ? i0 : (c1 ? gi : i1);     // uses old i0
            i0 = c0 ? gi : i0;
        }

        // distance update: branchless, 3 ops, reads old d0/d1/d2.
        const float nd1 = __builtin_amdgcn_fmed3f(d, d0, d1);
        const float nd2 = __builtin_amdgcn_fmed3f(d, d1, d2);
        d0 = fminf(d0, d);
        d1 = nd1;
        d2 = nd2;
    }

    float* pd = part_d + (size_t)g * (S_CHUNKS * 3) + s * 3;
    int*   pi = part_i + (size_t)g * (S_CHUNKS * 3) + s * 3;
    pd[0] = d0; pd[1] = d1; pd[2] = d2;
    pi[0] = i0; pi[1] = i1; pi[2] = i2;
}

// ---------------------------------------------------------------------------
// Merge S*3 exact candidates (ascending chunk = ascending index => identical
// tie-breaks to the full scan), compute normalized inverse-distance weights.
// ---------------------------------------------------------------------------
__launch_bounds__(256)
__global__ void knn_merge(const float* __restrict__ part_d,
                          const int*   __restrict__ part_i,
                          int*  __restrict__ idx_out,   // [B*N_UP,3]
                          float* __restrict__ w_out)    // [B*N_UP,3]
{
    const int g = blockIdx.x * 256 + threadIdx.x;
    const float4* pd = (const float4*)(part_d + (size_t)g * (S_CHUNKS * 3));
    const int4*   pi = (const int4*)(part_i + (size_t)g * (S_CHUNKS * 3));

    float d0 = 1e30f, d1 = 1e30f, d2 = 1e30f;
    int   i0 = 0,     i1 = 0,     i2 = 0;

#pragma unroll
    for (int q = 0; q < (S_CHUNKS * 3) / 4; ++q) {
        const float4 dv = pd[q];
        const int4   iv = pi[q];
        const float dd[4] = {dv.x, dv.y, dv.z, dv.w};
        const int   ii[4] = {iv.x, iv.y, iv.z, iv.w};
#pragma unroll
        for (int j = 0; j < 4; ++j) {
            const float d = dd[j];
            const int   m = ii[j];
            const bool c2 = d < d2;
            const bool c1 = d < d1;
            const bool c0 = d < d0;
            if (c2) {
                i2 = c1 ? i1 : m;
                i1 = c0 ? i0 : (c1 ? m : i1);
                i0 = c0 ? m : i0;
            }
            const float nd1 = __builtin_amdgcn_fmed3f(d, d0, d1);
            const float nd2 = __builtin_amdgcn_fmed3f(d, d1, d2);
            d0 = fminf(d0, d);
            d1 = nd1;
            d2 = nd2;
        }
    }

    const float w0 = 1.0f / (d0 + 1e-8f);
    const float w1 = 1.0f / (d1 + 1e-8f);
    const float w2 = 1.0f / (d2 + 1e-8f);
    const float s  = (w0 + w1) + w2;
    idx_out[(size_t)g * 3 + 0] = i0;
    idx_out[(size_t)g * 3 + 1] = i1;
    idx_out[(size_t)g * 3 + 2] = i2;
    w_out[(size_t)g * 3 + 0] = w0 / s;
    w_out[(size_t)g * 3 + 1] = w1 / s;
    w_out[(size_t)g * 3 + 2] = w2 / s;
}

// ---------------------------------------------------------------------------
// f32 -> bf16 conversion, 4 elements/thread
// ---------------------------------------------------------------------------
__launch_bounds__(256)
__global__ void cvt_bf16(const float* __restrict__ src, unsigned short* __restrict__ dst) {
    const size_t i = (size_t)blockIdx.x * 256 + threadIdx.x;
    const float4 v = ((const float4*)src)[i];
    ushort4 o;
    o.x = f2bf(v.x); o.y = f2bf(v.y); o.z = f2bf(v.z); o.w = f2bf(v.w);
    ((ushort4*)dst)[i] = o;
}

// ---------------------------------------------------------------------------
// bf16 MFMA GEMM: C[m,n] = sum_k A[m,k]*W[n,k] (+bias) (+interp gather)
// 128x128 tile, BK=32, 256 threads = 4 waves (2x2 of 64x64), 16x16x32 MFMA.
// m97-style global_load_lds width-16 staging.
// ---------------------------------------------------------------------------
template<bool INTERP>
__launch_bounds__(256)
__global__ void gemm_bf16(const unsigned short* __restrict__ A,  // [M,K] bf16
                          const unsigned short* __restrict__ W,  // [N,K] bf16
                          const float* __restrict__ bias,        // [N]
                          float* __restrict__ C,                 // [M,N] f32
                          const int K, const int N,
                          const int* __restrict__ knn_idx,       // [M,3]
                          const float* __restrict__ knn_w,       // [M,3]
                          const float* __restrict__ down_f)      // [B*N_DOWN,N]
{
    __shared__ __align__(16) unsigned short As[128 * 32];
    __shared__ __align__(16) unsigned short Bs[128 * 32];
    __shared__ int   sI[128 * 3];
    __shared__ float sV[128 * 3];

    const int tid  = threadIdx.x;
    const int lane = tid & 63;
    const int wv   = tid >> 6;
    const int wrow = (wv >> 1) * 64;
    const int wcol = (wv & 1) * 64;
    const int quad = lane >> 4;
    const int l16  = lane & 15;
    const int m0   = blockIdx.y * 128;
    const int n0   = blockIdx.x * 128;

    if (INTERP) {
        for (int t = tid; t < 384; t += 256) {
            sI[t] = knn_idx[(size_t)m0 * 3 + t];
            sV[t] = knn_w[(size_t)m0 * 3 + t];
        }
    }

    f32x4 acc[4][4];
#pragma unroll
    for (int i = 0; i < 4; ++i)
#pragma unroll
        for (int j = 0; j < 4; ++j) {
            acc[i][j][0] = 0.f; acc[i][j][1] = 0.f;
            acc[i][j][2] = 0.f; acc[i][j][3] = 0.f;
        }

    // staging geometry: LDS tile is [row][32k] bf16 (64 B rows); each wave
    // covers 2 KiB as two 1 KiB chunks of lane*16.
    const int o0 = wv * 2048 + lane * 16;
    const int o1 = o0 + 1024;
    const int r0 = o0 >> 6, kk0 = o0 & 63;
    const int r1 = o1 >> 6, kk1 = o1 & 63;
    const char* Ab = (const char*)A;
    const char* Wb = (const char*)W;
    const size_t Ks = (size_t)K;

    for (int k0 = 0; k0 < K; k0 += 32) {
        __syncthreads();   // previous iter's ds_reads done before overwrite
        load_lds_128(Ab + ((size_t)(m0 + r0) * Ks + k0) * 2 + kk0, (char*)As + o0);
        load_lds_128(Ab + ((size_t)(m0 + r1) * Ks + k0) * 2 + kk1, (char*)As + o1);
        load_lds_128(Wb + ((size_t)(n0 + r0) * Ks + k0) * 2 + kk0, (char*)Bs + o0);
        load_lds_128(Wb + ((size_t)(n0 + r1) * Ks + k0) * 2 + kk1, (char*)Bs + o1);
        __syncthreads();   // vmcnt(0) drained by compiler before barrier

        bf16x8 af[4], bw[4];
#pragma unroll
        for (int i = 0; i < 4; ++i)
            af[i] = *(const bf16x8*)(As + (wrow + i * 16 + l16) * 32 + quad * 8);
#pragma unroll
        for (int j = 0; j < 4; ++j)
            bw[j] = *(const bf16x8*)(Bs + (wcol + j * 16 + l16) * 32 + quad * 8);
#pragma unroll
        for (int i = 0; i < 4; ++i)
#pragma unroll
            for (int j = 0; j < 4; ++j)
                acc[i][j] = __builtin_amdgcn_mfma_f32_16x16x32_bf16(
                    af[i], bw[j], acc[i][j], 0, 0, 0);
    }

    float bv[4];
#pragma unroll
    for (int j = 0; j < 4; ++j) bv[j] = bias[n0 + wcol + j * 16 + l16];

#pragma unroll
    for (int i = 0; i < 4; ++i) {
#pragma unroll
        for (int r = 0; r < 4; ++r) {
            const int row = m0 + wrow + i * 16 + quad * 4 + r;  // C/D: row=quad*4+reg
            float* crow = C + (size_t)row * N;
            if (INTERP) {
                const int lr3  = (row - m0) * 3;
                const int base = (row >> 14) * N_DOWN;          // batch * N_DOWN
                const float w0 = sV[lr3 + 0], w1 = sV[lr3 + 1], w2 = sV[lr3 + 2];
                const float* f0 = down_f + (size_t)(base + sI[lr3 + 0]) * N;
                const float* f1 = down_f + (size_t)(base + sI[lr3 + 1]) * N;
                const float* f2 = down_f + (size_t)(base + sI[lr3 + 2]) * N;
#pragma unroll
                for (int j = 0; j < 4; ++j) {
                    const int c = n0 + wcol + j * 16 + l16;     // C/D: col=lane&15
                    crow[c] = acc[i][j][r] + bv[j] + w0 * f0[c] + w1 * f1[c] + w2 * f2[c];
                }
            } else {
#pragma unroll
                for (int j = 0; j < 4; ++j) {
                    const int c = n0 + wcol + j * 16 + l16;
                    crow[c] = acc[i][j][r] + bv[j];
                }
            }
        }
    }
}

// ---------------------------------------------------------------------------
extern "C" void kernel_launch(void* const* d_in, const int* in_sizes, int n_in,
                              void* d_out, int out_size, void* d_ws, size_t ws_size,
                              hipStream_t stream) {
    const float* up_points     = (const float*)d_in[0];
    const float* up_features   = (const float*)d_in[1];
    const float* down_points   = (const float*)d_in[2];
    const float* down_features = (const float*)d_in[3];
    const float* W_up          = (const float*)d_in[4];
    const float* b_up          = (const float*)d_in[5];
    const float* W_down        = (const float*)d_in[6];
    const float* b_down        = (const float*)d_in[7];
    float* out = (float*)d_out;

    // workspace layout (all offsets 256B-aligned by construction)
    char* ws = (char*)d_ws;
    size_t off = 0;
    float* down_f = (float*)(ws + off);             off += (size_t)B_ * N_DOWN * C_OUT_ * 4;      // 33.6 MB
    int*   knn_idx = (int*)(ws + off);              off += (size_t)B_ * N_UP * 3 * 4;             // 0.8 MB
    float* knn_w   = (float*)(ws + off);            off += (size_t)B_ * N_UP * 3 * 4;             // 0.8 MB
    float* part_d  = (float*)(ws + off);            off += (size_t)B_ * N_UP * S_CHUNKS * 3 * 4;  // 6.3 MB
    int*   part_i  = (int*)(ws + off);              off += (size_t)B_ * N_UP * S_CHUNKS * 3 * 4;  // 6.3 MB
    float4* pts4   = (float4*)(ws + off);           off += (size_t)B_ * N_DOWN * 16;              // 0.26 MB
    unsigned short* upf_bf = (unsigned short*)(ws + off); off += (size_t)B_ * N_UP * C_UP_ * 2;   // 50.3 MB
    unsigned short* dnf_bf = (unsigned short*)(ws + off); off += (size_t)B_ * N_DOWN * C_DOWN_ * 2; // 16.8 MB
    unsigned short* wup_bf = (unsigned short*)(ws + off); off += (size_t)C_OUT_ * C_UP_ * 2;      // 0.4 MB
    unsigned short* wdn_bf = (unsigned short*)(ws + off); off += (size_t)C_OUT_ * C_DOWN_ * 2;    // 0.5 MB

    // 1) KNN pipeline
    prep_pts4<<<(B_ * N_DOWN) / 256, 256, 0, stream>>>(down_points, pts4);
    knn_chunk<<<dim3(N_UP / 256, B_, S_CHUNKS), 256, 0, stream>>>(
        up_points, pts4, part_d, part_i);
    knn_merge<<<(B_ * N_UP) / 256, 256, 0, stream>>>(part_d, part_i, knn_idx, knn_w);

    // 2) f32 -> bf16 conversions
    cvt_bf16<<<(B_ * N_UP * C_UP_) / 1024, 256, 0, stream>>>(up_features, upf_bf);
    cvt_bf16<<<(B_ * N_DOWN * C_DOWN_) / 1024, 256, 0, stream>>>(down_features, dnf_bf);
    cvt_bf16<<<(C_OUT_ * C_UP_) / 1024, 256, 0, stream>>>(W_up, wup_bf);
    cvt_bf16<<<(C_OUT_ * C_DOWN_) / 1024, 256, 0, stream>>>(W_down, wdn_bf);

    // 3) down_f = down_features @ W_down^T + b_down   [B*N_DOWN, 512]
    gemm_bf16<false><<<dim3(C_OUT_ / 128, (B_ * N_DOWN) / 128), 256, 0, stream>>>(
        dnf_bf, wdn_bf, b_down, down_f, C_DOWN_, C_OUT_, nullptr, nullptr, nullptr);

    // 4) out = up_features @ W_up^T + b_up + interp(down_f)   [B*N_UP, 512]
    gemm_bf16<true><<<dim3(C_OUT_ / 128, (B_ * N_UP) / 128), 256, 0, stream>>>(
        upf_bf, wup_bf, b_up, out, C_UP_, C_OUT_, knn_idx, knn_w, down_f);
}

// Round 3
// 457.198 us; speedup vs baseline: 1.1084x; 1.0016x over previous
//
#include <hip/hip_runtime.h>

// Problem constants (from reference)
constexpr int B_     = 4;
constexpr int N_UP   = 16384;
constexpr int N_DOWN = 4096;
constexpr int C_UP_  = 384;
constexpr int C_DOWN_= 512;
constexpr int C_OUT_ = 512;

// KNN chunking
constexpr int S_CHUNKS = 8;                // candidate chunks
constexpr int CH       = N_DOWN / S_CHUNKS; // 512 candidates per chunk

typedef __attribute__((ext_vector_type(8))) short bf16x8;
typedef __attribute__((ext_vector_type(4))) float f32x4;
typedef __attribute__((ext_vector_type(4))) float f4v;

// f32 -> bf16 round-to-nearest-even (bit-exact, no API dependence)
__device__ inline unsigned short f2bf(float f) {
    unsigned int u = __float_as_uint(f);
    return (unsigned short)((u + 0x7FFFu + ((u >> 16) & 1u)) >> 16);
}

// async global->LDS, 16B per lane. HW: dest = wave-uniform base + lane*16,
// so lds must be computed as base + lane*16 in lane order (it is, below).
__device__ inline void load_lds_128(const void* g, void* l) {
    __builtin_amdgcn_global_load_lds(
        (const __attribute__((address_space(1))) unsigned int*)g,
        (__attribute__((address_space(3))) unsigned int*)l, 16, 0, 0);
}

// ---------------------------------------------------------------------------
// pts4[b][m] = {x, y, z, (x*x+y*y)+z*z}   (ref rounding order, no contract)
// ---------------------------------------------------------------------------
__global__ void prep_pts4(const float* __restrict__ down_pts, float4* __restrict__ pts4) {
#pragma clang fp contract(off)
    const int i = blockIdx.x * 256 + threadIdx.x;   // 0 .. B*N_DOWN-1
    const float x = down_pts[i * 3 + 0];
    const float y = down_pts[i * 3 + 1];
    const float z = down_pts[i * 3 + 2];
    float4 p; p.x = x; p.y = y; p.z = z; p.w = (x * x + y * y) + z * z;
    pts4[i] = p;
}

// ---------------------------------------------------------------------------
// Per-chunk exact top-3. Grid (N_UP/256, B, S_CHUNKS); 1 query per thread.
//
// Candidate points are WAVE-UNIFORM -> read them through address-space(4)
// (constant) with a uniform index so the compiler emits s_load into SGPRs:
// no LDS traffic, no VALU address math, candidate components are scalar
// operands (<=1 SGPR per VALU op, legal). gi = mbase+m is pure SALU.
//
// dist = fmaf(-2, cross, u2 + d2) -- bit-identical to ref's
// (u2+d2) - 2*cross (2*cross exact, single rounding).
// Distance tuple: branchless min/med3 (stable-insert-exact, incl. ties).
// Index tuple: straight-line 5 cndmask (no divergent branch).
// ---------------------------------------------------------------------------
__launch_bounds__(256)
__global__ void knn_chunk(const float* __restrict__ up_pts,   // [B,N_UP,3]
                          const float4* __restrict__ pts4,    // [B,N_DOWN]
                          float* __restrict__ part_d,         // [B*N_UP, S*3]
                          int*   __restrict__ part_i)
{
#pragma clang fp contract(off)
    const int b = blockIdx.y;
    const int s = blockIdx.z;
    const int mbase = s * CH;

    typedef __attribute__((address_space(4))) const f4v cst_f4;
    const cst_f4* sp = (const cst_f4*)(pts4 + (size_t)b * N_DOWN + mbase);

    const int n0 = blockIdx.x * 256;
    const int g  = b * N_UP + n0 + threadIdx.x;

    const float qx = up_pts[(size_t)g * 3 + 0];
    const float qy = up_pts[(size_t)g * 3 + 1];
    const float qz = up_pts[(size_t)g * 3 + 2];
    const float qu = (qx * qx + qy * qy) + qz * qz;

    float d0 = 1e30f, d1 = 1e30f, d2 = 1e30f;
    int   i0 = 0,     i1 = 0,     i2 = 0;

#pragma unroll 4
    for (int m = 0; m < CH; ++m) {
        const f4v p = sp[m];                       // s_load -> SGPRs
        const int gi = mbase + m;                  // SALU
        const float cr = (qx * p.x + qy * p.y) + qz * p.z;
        const float d  = __builtin_fmaf(-2.0f, cr, qu + p.w);

        const bool c2 = d < d2;
        const bool c1 = d < d1;
        const bool c0 = d < d0;

        // index update: 5 cndmasks, straight-line (reads old i1/i0 first)
        { const int t = c2 ? gi : i2; i2 = c1 ? i1 : t; }
        { const int t = c1 ? gi : i1; i1 = c0 ? i0 : t; }
        i0 = c0 ? gi : i0;

        // distance update: branchless, 3 ops, reads old d0/d1/d2.
        const float nd1 = __builtin_amdgcn_fmed3f(d, d0, d1);
        const float nd2 = __builtin_amdgcn_fmed3f(d, d1, d2);
        d0 = fminf(d0, d);
        d1 = nd1;
        d2 = nd2;
    }

    float* pd = part_d + (size_t)g * (S_CHUNKS * 3) + s * 3;
    int*   pi = part_i + (size_t)g * (S_CHUNKS * 3) + s * 3;
    pd[0] = d0; pd[1] = d1; pd[2] = d2;
    pi[0] = i0; pi[1] = i1; pi[2] = i2;
}

// ---------------------------------------------------------------------------
// Merge S*3 exact candidates (ascending chunk = ascending index => identical
// tie-breaks to the full scan), compute normalized inverse-distance weights.
// ---------------------------------------------------------------------------
__launch_bounds__(256)
__global__ void knn_merge(const float* __restrict__ part_d,
                          const int*   __restrict__ part_i,
                          int*  __restrict__ idx_out,   // [B*N_UP,3]
                          float* __restrict__ w_out)    // [B*N_UP,3]
{
    const int g = blockIdx.x * 256 + threadIdx.x;
    const float4* pd = (const float4*)(part_d + (size_t)g * (S_CHUNKS * 3));
    const int4*   pi = (const int4*)(part_i + (size_t)g * (S_CHUNKS * 3));

    float d0 = 1e30f, d1 = 1e30f, d2 = 1e30f;
    int   i0 = 0,     i1 = 0,     i2 = 0;

#pragma unroll
    for (int q = 0; q < (S_CHUNKS * 3) / 4; ++q) {
        const float4 dv = pd[q];
        const int4   iv = pi[q];
        const float dd[4] = {dv.x, dv.y, dv.z, dv.w};
        const int   ii[4] = {iv.x, iv.y, iv.z, iv.w};
#pragma unroll
        for (int j = 0; j < 4; ++j) {
            const float d = dd[j];
            const int   m = ii[j];
            const bool c2 = d < d2;
            const bool c1 = d < d1;
            const bool c0 = d < d0;
            { const int t = c2 ? m : i2; i2 = c1 ? i1 : t; }
            { const int t = c1 ? m : i1; i1 = c0 ? i0 : t; }
            i0 = c0 ? m : i0;
            const float nd1 = __builtin_amdgcn_fmed3f(d, d0, d1);
            const float nd2 = __builtin_amdgcn_fmed3f(d, d1, d2);
            d0 = fminf(d0, d);
            d1 = nd1;
            d2 = nd2;
        }
    }

    const float w0 = 1.0f / (d0 + 1e-8f);
    const float w1 = 1.0f / (d1 + 1e-8f);
    const float w2 = 1.0f / (d2 + 1e-8f);
    const float s  = (w0 + w1) + w2;
    idx_out[(size_t)g * 3 + 0] = i0;
    idx_out[(size_t)g * 3 + 1] = i1;
    idx_out[(size_t)g * 3 + 2] = i2;
    w_out[(size_t)g * 3 + 0] = w0 / s;
    w_out[(size_t)g * 3 + 1] = w1 / s;
    w_out[(size_t)g * 3 + 2] = w2 / s;
}

// ---------------------------------------------------------------------------
// f32 -> bf16 conversion, 4 elements/thread
// ---------------------------------------------------------------------------
__launch_bounds__(256)
__global__ void cvt_bf16(const float* __restrict__ src, unsigned short* __restrict__ dst) {
    const size_t i = (size_t)blockIdx.x * 256 + threadIdx.x;
    const float4 v = ((const float4*)src)[i];
    ushort4 o;
    o.x = f2bf(v.x); o.y = f2bf(v.y); o.z = f2bf(v.z); o.w = f2bf(v.w);
    ((ushort4*)dst)[i] = o;
}

// ---------------------------------------------------------------------------
// bf16 MFMA GEMM: C[m,n] = sum_k A[m,k]*W[n,k] (+bias) (+interp gather)
// 128x128 tile, BK=32, 256 threads = 4 waves (2x2 of 64x64), 16x16x32 MFMA.
// m97-style global_load_lds width-16 staging.
// ---------------------------------------------------------------------------
template<bool INTERP>
__launch_bounds__(256)
__global__ void gemm_bf16(const unsigned short* __restrict__ A,  // [M,K] bf16
                          const unsigned short* __restrict__ W,  // [N,K] bf16
                          const float* __restrict__ bias,        // [N]
                          float* __restrict__ C,                 // [M,N] f32
                          const int K, const int N,
                          const int* __restrict__ knn_idx,       // [M,3]
                          const float* __restrict__ knn_w,       // [M,3]
                          const float* __restrict__ down_f)      // [B*N_DOWN,N]
{
    __shared__ __align__(16) unsigned short As[128 * 32];
    __shared__ __align__(16) unsigned short Bs[128 * 32];
    __shared__ int   sI[128 * 3];
    __shared__ float sV[128 * 3];

    const int tid  = threadIdx.x;
    const int lane = tid & 63;
    const int wv   = tid >> 6;
    const int wrow = (wv >> 1) * 64;
    const int wcol = (wv & 1) * 64;
    const int quad = lane >> 4;
    const int l16  = lane & 15;
    const int m0   = blockIdx.y * 128;
    const int n0   = blockIdx.x * 128;

    if (INTERP) {
        for (int t = tid; t < 384; t += 256) {
            sI[t] = knn_idx[(size_t)m0 * 3 + t];
            sV[t] = knn_w[(size_t)m0 * 3 + t];
        }
    }

    f32x4 acc[4][4];
#pragma unroll
    for (int i = 0; i < 4; ++i)
#pragma unroll
        for (int j = 0; j < 4; ++j) {
            acc[i][j][0] = 0.f; acc[i][j][1] = 0.f;
            acc[i][j][2] = 0.f; acc[i][j][3] = 0.f;
        }

    // staging geometry: LDS tile is [row][32k] bf16 (64 B rows); each wave
    // covers 2 KiB as two 1 KiB chunks of lane*16.
    const int o0 = wv * 2048 + lane * 16;
    const int o1 = o0 + 1024;
    const int r0 = o0 >> 6, kk0 = o0 & 63;
    const int r1 = o1 >> 6, kk1 = o1 & 63;
    const char* Ab = (const char*)A;
    const char* Wb = (const char*)W;
    const size_t Ks = (size_t)K;

    for (int k0 = 0; k0 < K; k0 += 32) {
        __syncthreads();   // previous iter's ds_reads done before overwrite
        load_lds_128(Ab + ((size_t)(m0 + r0) * Ks + k0) * 2 + kk0, (char*)As + o0);
        load_lds_128(Ab + ((size_t)(m0 + r1) * Ks + k0) * 2 + kk1, (char*)As + o1);
        load_lds_128(Wb + ((size_t)(n0 + r0) * Ks + k0) * 2 + kk0, (char*)Bs + o0);
        load_lds_128(Wb + ((size_t)(n0 + r1) * Ks + k0) * 2 + kk1, (char*)Bs + o1);
        __syncthreads();   // vmcnt(0) drained by compiler before barrier

        bf16x8 af[4], bw[4];
#pragma unroll
        for (int i = 0; i < 4; ++i)
            af[i] = *(const bf16x8*)(As + (wrow + i * 16 + l16) * 32 + quad * 8);
#pragma unroll
        for (int j = 0; j < 4; ++j)
            bw[j] = *(const bf16x8*)(Bs + (wcol + j * 16 + l16) * 32 + quad * 8);
#pragma unroll
        for (int i = 0; i < 4; ++i)
#pragma unroll
            for (int j = 0; j < 4; ++j)
                acc[i][j] = __builtin_amdgcn_mfma_f32_16x16x32_bf16(
                    af[i], bw[j], acc[i][j], 0, 0, 0);
    }

    float bv[4];
#pragma unroll
    for (int j = 0; j < 4; ++j) bv[j] = bias[n0 + wcol + j * 16 + l16];

#pragma unroll
    for (int i = 0; i < 4; ++i) {
#pragma unroll
        for (int r = 0; r < 4; ++r) {
            const int row = m0 + wrow + i * 16 + quad * 4 + r;  // C/D: row=quad*4+reg
            float* crow = C + (size_t)row * N;
            if (INTERP) {
                const int lr3  = (row - m0) * 3;
                const int base = (row >> 14) * N_DOWN;          // batch * N_DOWN
                const float w0 = sV[lr3 + 0], w1 = sV[lr3 + 1], w2 = sV[lr3 + 2];
                const float* f0 = down_f + (size_t)(base + sI[lr3 + 0]) * N;
                const float* f1 = down_f + (size_t)(base + sI[lr3 + 1]) * N;
                const float* f2 = down_f + (size_t)(base + sI[lr3 + 2]) * N;
#pragma unroll
                for (int j = 0; j < 4; ++j) {
                    const int c = n0 + wcol + j * 16 + l16;     // C/D: col=lane&15
                    crow[c] = acc[i][j][r] + bv[j] + w0 * f0[c] + w1 * f1[c] + w2 * f2[c];
                }
            } else {
#pragma unroll
                for (int j = 0; j < 4; ++j) {
                    const int c = n0 + wcol + j * 16 + l16;
                    crow[c] = acc[i][j][r] + bv[j];
                }
            }
        }
    }
}

// ---------------------------------------------------------------------------
extern "C" void kernel_launch(void* const* d_in, const int* in_sizes, int n_in,
                              void* d_out, int out_size, void* d_ws, size_t ws_size,
                              hipStream_t stream) {
    const float* up_points     = (const float*)d_in[0];
    const float* up_features   = (const float*)d_in[1];
    const float* down_points   = (const float*)d_in[2];
    const float* down_features = (const float*)d_in[3];
    const float* W_up          = (const float*)d_in[4];
    const float* b_up          = (const float*)d_in[5];
    const float* W_down        = (const float*)d_in[6];
    const float* b_down        = (const float*)d_in[7];
    float* out = (float*)d_out;

    // workspace layout (all offsets 256B-aligned by construction)
    char* ws = (char*)d_ws;
    size_t off = 0;
    float* down_f = (float*)(ws + off);             off += (size_t)B_ * N_DOWN * C_OUT_ * 4;      // 33.6 MB
    int*   knn_idx = (int*)(ws + off);              off += (size_t)B_ * N_UP * 3 * 4;             // 0.8 MB
    float* knn_w   = (float*)(ws + off);            off += (size_t)B_ * N_UP * 3 * 4;             // 0.8 MB
    float* part_d  = (float*)(ws + off);            off += (size_t)B_ * N_UP * S_CHUNKS * 3 * 4;  // 6.3 MB
    int*   part_i  = (int*)(ws + off);              off += (size_t)B_ * N_UP * S_CHUNKS * 3 * 4;  // 6.3 MB
    float4* pts4   = (float4*)(ws + off);           off += (size_t)B_ * N_DOWN * 16;              // 0.26 MB
    unsigned short* upf_bf = (unsigned short*)(ws + off); off += (size_t)B_ * N_UP * C_UP_ * 2;   // 50.3 MB
    unsigned short* dnf_bf = (unsigned short*)(ws + off); off += (size_t)B_ * N_DOWN * C_DOWN_ * 2; // 16.8 MB
    unsigned short* wup_bf = (unsigned short*)(ws + off); off += (size_t)C_OUT_ * C_UP_ * 2;      // 0.4 MB
    unsigned short* wdn_bf = (unsigned short*)(ws + off); off += (size_t)C_OUT_ * C_DOWN_ * 2;    // 0.5 MB

    // 1) KNN pipeline
    prep_pts4<<<(B_ * N_DOWN) / 256, 256, 0, stream>>>(down_points, pts4);
    knn_chunk<<<dim3(N_UP / 256, B_, S_CHUNKS), 256, 0, stream>>>(
        up_points, pts4, part_d, part_i);
    knn_merge<<<(B_ * N_UP) / 256, 256, 0, stream>>>(part_d, part_i, knn_idx, knn_w);

    // 2) f32 -> bf16 conversions
    cvt_bf16<<<(B_ * N_UP * C_UP_) / 1024, 256, 0, stream>>>(up_features, upf_bf);
    cvt_bf16<<<(B_ * N_DOWN * C_DOWN_) / 1024, 256, 0, stream>>>(down_features, dnf_bf);
    cvt_bf16<<<(C_OUT_ * C_UP_) / 1024, 256, 0, stream>>>(W_up, wup_bf);
    cvt_bf16<<<(C_OUT_ * C_DOWN_) / 1024, 256, 0, stream>>>(W_down, wdn_bf);

    // 3) down_f = down_features @ W_down^T + b_down   [B*N_DOWN, 512]
    gemm_bf16<false><<<dim3(C_OUT_ / 128, (B_ * N_DOWN) / 128), 256, 0, stream>>>(
        dnf_bf, wdn_bf, b_down, down_f, C_DOWN_, C_OUT_, nullptr, nullptr, nullptr);

    // 4) out = up_features @ W_up^T + b_up + interp(down_f)   [B*N_UP, 512]
    gemm_bf16<true><<<dim3(C_OUT_ / 128, (B_ * N_UP) / 128), 256, 0, stream>>>(
        upf_bf, wup_bf, b_up, out, C_UP_, C_OUT_, knn_idx, knn_w, down_f);
}